// Round 1
// baseline (164.317 us; speedup 1.0000x reference)
//
#include <hip/hip_runtime.h>
#include <cstddef>

constexpr int BH = 32;    // batch*heads
constexpr int N  = 8192;  // sequence
constexpr int D  = 64;    // dim
constexpr int BK = 64;    // bucket size
constexpr int NB = 128;   // N / BK buckets
constexpr int NC = 129;   // NB + 1 (padded sk)

typedef float v4f __attribute__((ext_vector_type(4)));  // native vector for NT builtins

// ---------------------------------------------------------------------------
// Kernel A (UNCHANGED from the 148-µs baseline): block per (bucket j, b);
// 8 independent non-temporal float4 loads per thread, in-wave suffix harmonic
// scan, shuffle reduce, one barrier, 3 KB LDS combine.
// ---------------------------------------------------------------------------
__global__ __launch_bounds__(256) void kA(const float* __restrict__ q,
                                          const float* __restrict__ k,
                                          float* __restrict__ qsum,
                                          float* __restrict__ ksum,
                                          float* __restrict__ kw,
                                          float* __restrict__ qfirst,
                                          float* __restrict__ W) {
  const int j = blockIdx.x, b = blockIdx.y;
  const int tid  = threadIdx.x;
  const int f    = tid & 15;      // float4 column
  const int rr   = tid >> 4;      // row-group 0..15 (rows 16p + rr)
  const int w    = tid >> 6;      // wave
  const int lane = tid & 63;
  const int base = j * BK;
  const size_t ob = ((size_t)b * NB + j) * D;

  const v4f* q4 = (const v4f*)(q + ((size_t)b * N + base) * D);
  const v4f* k4 = (const v4f*)(k + ((size_t)b * N + base) * D);

  // ---- 8 independent NT loads, all issued before any consumer
  v4f vq[4], vk[4];
#pragma unroll
  for (int p = 0; p < 4; ++p) vq[p] = __builtin_nontemporal_load(&q4[(16 * p + rr) * 16 + f]);
#pragma unroll
  for (int p = 0; p < 4; ++p) vk[p] = __builtin_nontemporal_load(&k4[(16 * p + rr) * 16 + f]);

  // ---- in-wave suffix harmonic scan (overlaps loads):
  // x[lane] = sum_{u>=lane} 1/(base+u+1)
  float x = 1.0f / (float)(base + lane + 1);
#pragma unroll
  for (int s = 1; s < 64; s <<= 1) {
    const float y = __shfl_down(x, s, 64);
    if (lane + s < 64) x += y;
  }
  float tw[4];
#pragma unroll
  for (int p = 0; p < 4; ++p) tw[p] = __shfl(x, 16 * p + rr, 64);

  // ---- accumulate
  float aq[4] = {0, 0, 0, 0}, ak[4] = {0, 0, 0, 0}, aw[4] = {0, 0, 0, 0};
#pragma unroll
  for (int p = 0; p < 4; ++p) {
    aq[0] += vq[p].x; aq[1] += vq[p].y; aq[2] += vq[p].z; aq[3] += vq[p].w;
    ak[0] += vk[p].x; ak[1] += vk[p].y; ak[2] += vk[p].z; ak[3] += vk[p].w;
    aw[0] += vk[p].x * tw[p]; aw[1] += vk[p].y * tw[p];
    aw[2] += vk[p].z * tw[p]; aw[3] += vk[p].w * tw[p];
  }

  // ---- reduce over the 4 row-groups resident in this wave (lane = (rr&3)*16+f)
#pragma unroll
  for (int c = 0; c < 4; ++c) {
    aq[c] += __shfl_xor(aq[c], 16, 64); aq[c] += __shfl_xor(aq[c], 32, 64);
    ak[c] += __shfl_xor(ak[c], 16, 64); ak[c] += __shfl_xor(ak[c], 32, 64);
    aw[c] += __shfl_xor(aw[c], 16, 64); aw[c] += __shfl_xor(aw[c], 32, 64);
  }

  __shared__ float red[3][4][D];   // 3 KB
  if (lane < 16) {                 // lane == f
    ((float4*)&red[0][w][0])[f] = make_float4(aq[0], aq[1], aq[2], aq[3]);
    ((float4*)&red[1][w][0])[f] = make_float4(ak[0], ak[1], ak[2], ak[3]);
    ((float4*)&red[2][w][0])[f] = make_float4(aw[0], aw[1], aw[2], aw[3]);
  }
  if (rr == 0) {                   // rows 16p+0, p=0 -> bucket row 0 (q)
    ((float4*)(qfirst + ob))[f] = make_float4(vq[0].x, vq[0].y, vq[0].z, vq[0].w);
  }
  if (tid == 0 && b == 0) W[j] = x;  // lane 0: full-bucket harmonic
  __syncthreads();

  if (tid < 192) {
    const int arr = tid >> 6, d = tid & 63;
    const float s = red[arr][0][d] + red[arr][1][d] + red[arr][2][d] + red[arr][3][d];
    float* dst = (arr == 0) ? qsum : (arr == 1) ? ksum : kw;
    dst[ob + d] = s;
  }
}

// ---------------------------------------------------------------------------
// Kernel BC: fused scan + scores + softmax. grid (16, BH).
// Replaces the old kB (64-block global prefix scan) + kC: each block
// recomputes the <=128-row exclusive prefixes of qsum/ksum locally
// (hierarchical 4x32 chunk scan, wave-uniform bounds) and writes sq rows
// straight into LDS `sqs` and skp rows straight into the XOR-swizzled
// `skpS` — the sq/skp global round-trip and one dispatch boundary are gone.
// qsum/ksum/kw are a 4-MB working set: L3-resident re-reads, hidden by
// 8 waves/CU.
// ---------------------------------------------------------------------------
__global__ __launch_bounds__(256) void kBC(const float* __restrict__ qsum,
                                           const float* __restrict__ ksum,
                                           const float* __restrict__ kw,
                                           const float* __restrict__ qfirst,
                                           const float* __restrict__ W,
                                           float* __restrict__ out) {
  const int tile = blockIdx.x, b = blockIdx.y;
  const int tid = threadIdx.x;
  const int T0 = tile * 8;
  const int Rneed = T0 + 8;        // rows of interest: sq rows T0..T0+7, skp cols 1..T0+7

  __shared__ float skpS[NB * D];   // 32 KB, float4-XOR-swizzled rows 0..T0+7
  __shared__ float sqs[8 * D];     // 2 KB
  __shared__ float chq[4 * D];     // chunk totals (q side)
  __shared__ float chk[4 * D];     // chunk totals (k side)
  __shared__ float Wl[NB];

  const int d = tid & 63;          // feature dim
  const int g = tid >> 6;          // wave = scan chunk 0..3 (rows g*32..g*32+31)
  const float* qs  = qsum   + (size_t)b * NB * D;
  const float* ks  = ksum   + (size_t)b * NB * D;
  const float* kwp = kw     + (size_t)b * NB * D;
  const float* qf  = qfirst + (size_t)b * NB * D;

  if (tid < NB) Wl[tid] = W[tid];
  if (tid < D)  skpS[tid] = 0.0f;  // pad row 0 (swizzle is identity for row 0)

  // ---- pass 1: per-chunk totals (only chunks below Rneed; wave-uniform)
  float cq = 0.0f, ck = 0.0f;
  const int gbase = g * 32;
  if (gbase < Rneed) {
    const int rmax = (Rneed - gbase < 32) ? (Rneed - gbase) : 32;
    for (int jj = 0; jj < rmax; ++jj) {
      const int r = gbase + jj;
      cq += qs[r * D + d];
      ck += ks[r * D + d];
    }
  }
  chq[g * D + d] = cq;
  chk[g * D + d] = ck;
  __syncthreads();

  // ---- exclusive chunk bases
  float pq = 0.0f, pk = 0.0f;
  for (int gg = 0; gg < g; ++gg) { pq += chq[gg * D + d]; pk += chk[gg * D + d]; }

  // ---- pass 2: sequential scan within chunk; emit sq/skp rows into LDS
  if (gbase < Rneed) {
    const int rmax = (Rneed - gbase < 32) ? (Rneed - gbase) : 32;
    for (int jj = 0; jj < rmax; ++jj) {
      const int r = gbase + jj;
      const float qv = qs[r * D + d];
      const float kv = ks[r * D + d];
      if ((unsigned)(r - T0) < 8u)     // sq rows T0..T0+7 (wave-uniform branch)
        sqs[(r - T0) * D + d] = (pq + qf[r * D + d]) / (float)(r * BK + 1);
      pq += qv;
      if (r < Rneed - 1) {             // skp col c = r+1 <= T0+7 (wave-uniform)
        const int c = r + 1;
        skpS[c * D + ((((d >> 2) + c) & 15) << 2) + (d & 3)] = pk * Wl[r] + kwp[r * D + d];
      }
      pk += kv;
    }
  }
  __syncthreads();

  // ---- scores + softmax (identical to the validated kC)
  const int jp = tid & 63, rep = tid >> 6;
  float acc0[2] = {0, 0}, acc1[2] = {0, 0};
  const float4* sk4 = (const float4*)skpS;
  const float4* sq4 = (const float4*)sqs;
#pragma unroll
  for (int d4 = 0; d4 < 16; ++d4) {
    const int slot = (d4 + jp) & 15;           // same slot for jp and jp+64
    const float4 k0 = sk4[jp * 16 + slot];
    const float4 k1 = sk4[(jp + 64) * 16 + slot];
#pragma unroll
    for (int ii = 0; ii < 2; ++ii) {
      const float4 s = sq4[(rep * 2 + ii) * 16 + d4];
      acc0[ii] += s.x * k0.x + s.y * k0.y + s.z * k0.z + s.w * k0.w;
      acc1[ii] += s.x * k1.x + s.y * k1.y + s.z * k1.z + s.w * k1.w;
    }
  }

#pragma unroll
  for (int ii = 0; ii < 2; ++ii) {
    const int i = T0 + rep * 2 + ii;
    const int j0 = jp, j1 = jp + 64;
    const float v0 = acc0[ii] * 0.125f, v1 = acc1[ii] * 0.125f;
    const bool val0 = (j0 <= i), val1 = (j1 <= i);
    float m = fmaxf(val0 ? v0 : -3.402823466e38f, val1 ? v1 : -3.402823466e38f);
#pragma unroll
    for (int s = 1; s < 64; s <<= 1) m = fmaxf(m, __shfl_xor(m, s, 64));
    const float e0 = val0 ? __expf(v0 - m) : 0.0f;
    const float e1 = val1 ? __expf(v1 - m) : 0.0f;
    float ss = e0 + e1;
#pragma unroll
    for (int s = 1; s < 64; s <<= 1) ss += __shfl_xor(ss, s, 64);
    const float rden = 1.0f / ss;
    float* orow = out + ((size_t)b * NB + i) * NC;
    orow[j0] = (j0 < i) ? e0 * rden : 0.0f;
    orow[j1] = (j1 < i) ? e1 * rden : 0.0f;
    if (jp == 0) orow[128] = 0.0f;
  }
}

// ---------------------------------------------------------------------------
extern "C" void kernel_launch(void* const* d_in, const int* in_sizes, int n_in,
                              void* d_out, int out_size, void* d_ws, size_t ws_size,
                              hipStream_t stream) {
  const float* q = (const float*)d_in[0];
  const float* k = (const float*)d_in[1];
  float* out = (float*)d_out;

  float* ws     = (float*)d_ws;
  float* qsum   = ws;                            // BH*NB*D
  float* ksum   = qsum   + (size_t)BH * NB * D;
  float* kw     = ksum   + (size_t)BH * NB * D;
  float* qfirst = kw     + (size_t)BH * NB * D;
  float* W      = qfirst + (size_t)BH * NB * D;  // NB

  kA<<<dim3(NB, BH), 256, 0, stream>>>(q, k, qsum, ksum, kw, qfirst, W);
  kBC<<<dim3(16, BH), 256, 0, stream>>>(qsum, ksum, kw, qfirst, W, out);
}

// Round 2
// 148.266 us; speedup vs baseline: 1.1083x; 1.1083x over previous
//
#include <hip/hip_runtime.h>
#include <cstddef>

constexpr int BH = 32;    // batch*heads
constexpr int N  = 8192;  // sequence
constexpr int D  = 64;    // dim
constexpr int BK = 64;    // bucket size
constexpr int NB = 128;   // N / BK buckets
constexpr int NC = 129;   // NB + 1 (padded sk)

typedef float v4f __attribute__((ext_vector_type(4)));  // native vector for NT builtins

// ---------------------------------------------------------------------------
// Kernel A (UNCHANGED from the verified 148-µs baseline): block per (bucket
// j, b); 8 independent non-temporal float4 loads per thread, in-wave suffix
// harmonic scan, shuffle reduce, one barrier, 3 KB LDS combine.
// ---------------------------------------------------------------------------
__global__ __launch_bounds__(256) void kA(const float* __restrict__ q,
                                          const float* __restrict__ k,
                                          float* __restrict__ qsum,
                                          float* __restrict__ ksum,
                                          float* __restrict__ kw,
                                          float* __restrict__ qfirst,
                                          float* __restrict__ W) {
  const int j = blockIdx.x, b = blockIdx.y;
  const int tid  = threadIdx.x;
  const int f    = tid & 15;      // float4 column
  const int rr   = tid >> 4;      // row-group 0..15 (rows 16p + rr)
  const int w    = tid >> 6;      // wave
  const int lane = tid & 63;
  const int base = j * BK;
  const size_t ob = ((size_t)b * NB + j) * D;

  const v4f* q4 = (const v4f*)(q + ((size_t)b * N + base) * D);
  const v4f* k4 = (const v4f*)(k + ((size_t)b * N + base) * D);

  // ---- 8 independent NT loads, all issued before any consumer
  v4f vq[4], vk[4];
#pragma unroll
  for (int p = 0; p < 4; ++p) vq[p] = __builtin_nontemporal_load(&q4[(16 * p + rr) * 16 + f]);
#pragma unroll
  for (int p = 0; p < 4; ++p) vk[p] = __builtin_nontemporal_load(&k4[(16 * p + rr) * 16 + f]);

  // ---- in-wave suffix harmonic scan (overlaps loads):
  // x[lane] = sum_{u>=lane} 1/(base+u+1)
  float x = 1.0f / (float)(base + lane + 1);
#pragma unroll
  for (int s = 1; s < 64; s <<= 1) {
    const float y = __shfl_down(x, s, 64);
    if (lane + s < 64) x += y;
  }
  float tw[4];
#pragma unroll
  for (int p = 0; p < 4; ++p) tw[p] = __shfl(x, 16 * p + rr, 64);

  // ---- accumulate
  float aq[4] = {0, 0, 0, 0}, ak[4] = {0, 0, 0, 0}, aw[4] = {0, 0, 0, 0};
#pragma unroll
  for (int p = 0; p < 4; ++p) {
    aq[0] += vq[p].x; aq[1] += vq[p].y; aq[2] += vq[p].z; aq[3] += vq[p].w;
    ak[0] += vk[p].x; ak[1] += vk[p].y; ak[2] += vk[p].z; ak[3] += vk[p].w;
    aw[0] += vk[p].x * tw[p]; aw[1] += vk[p].y * tw[p];
    aw[2] += vk[p].z * tw[p]; aw[3] += vk[p].w * tw[p];
  }

  // ---- reduce over the 4 row-groups resident in this wave (lane = (rr&3)*16+f)
#pragma unroll
  for (int c = 0; c < 4; ++c) {
    aq[c] += __shfl_xor(aq[c], 16, 64); aq[c] += __shfl_xor(aq[c], 32, 64);
    ak[c] += __shfl_xor(ak[c], 16, 64); ak[c] += __shfl_xor(ak[c], 32, 64);
    aw[c] += __shfl_xor(aw[c], 16, 64); aw[c] += __shfl_xor(aw[c], 32, 64);
  }

  __shared__ float red[3][4][D];   // 3 KB
  if (lane < 16) {                 // lane == f
    ((float4*)&red[0][w][0])[f] = make_float4(aq[0], aq[1], aq[2], aq[3]);
    ((float4*)&red[1][w][0])[f] = make_float4(ak[0], ak[1], ak[2], ak[3]);
    ((float4*)&red[2][w][0])[f] = make_float4(aw[0], aw[1], aw[2], aw[3]);
  }
  if (rr == 0) {                   // rows 16p+0, p=0 -> bucket row 0 (q)
    ((float4*)(qfirst + ob))[f] = make_float4(vq[0].x, vq[0].y, vq[0].z, vq[0].w);
  }
  if (tid == 0 && b == 0) W[j] = x;  // lane 0: full-bucket harmonic
  __syncthreads();

  if (tid < 192) {
    const int arr = tid >> 6, d = tid & 63;
    const float s = red[arr][0][d] + red[arr][1][d] + red[arr][2][d] + red[arr][3][d];
    float* dst = (arr == 0) ? qsum : (arr == 1) ? ksum : kw;
    dst[ob + d] = s;
  }
}

// ---------------------------------------------------------------------------
// Kernel B: prefix scan. grid (2, BH): x=0 -> q side (sq), x=1 -> k side (skp).
// CHANGED vs baseline: 512 threads (8 chunks x depth 16) instead of 256
// (4 chunks x depth 32) — halves the serial scan depth and doubles resident
// waves on the 64 active CUs. Semantics identical.
// ---------------------------------------------------------------------------
__global__ __launch_bounds__(512) void kB(const float* __restrict__ qsum,
                                          const float* __restrict__ ksum,
                                          const float* __restrict__ kw,
                                          const float* __restrict__ qfirst,
                                          const float* __restrict__ W,
                                          float* __restrict__ sq,
                                          float* __restrict__ skp) {
  const int side = blockIdx.x;
  const int b    = blockIdx.y;
  const int tid  = threadIdx.x;
  const int d    = tid & 63;
  const int jg   = tid >> 6;       // chunk 0..7, rows jg*16 .. jg*16+15

  __shared__ float buf[NB * D];    // 32 KB
  __shared__ float tot[8 * D];     // 2 KB
  __shared__ float Wl[NB];

  const float* src = (side == 0 ? qsum : ksum) + (size_t)b * NB * D;
  {
    const float4* g4 = (const float4*)src;
    float4* l4 = (float4*)buf;
    for (int u = tid; u < NB * D / 4; u += 512) l4[u] = g4[u];
    if (side == 1 && tid < NB) Wl[tid] = W[tid];
  }
  __syncthreads();

  float t0 = 0.0f;
  for (int jj = 0; jj < 16; ++jj) t0 += buf[(jg * 16 + jj) * D + d];
  tot[jg * D + d] = t0;
  __syncthreads();

  float pre = 0.0f;
  for (int g = 0; g < jg; ++g) pre += tot[g * D + d];

  if (side == 0) {
    for (int jj = 0; jj < 16; ++jj) {
      const int j = jg * 16 + jj;
      const size_t o = ((size_t)b * NB + j) * D + d;
      sq[o] = (pre + qfirst[o]) / (float)(j * BK + 1);
      pre += buf[j * D + d];
    }
  } else {
    if (tid < D) skp[(size_t)b * NC * D + tid] = 0.0f;  // pad row 0
    for (int jj = 0; jj < 16; ++jj) {
      const int j = jg * 16 + jj;
      const size_t o = ((size_t)b * NB + j) * D + d;
      skp[((size_t)b * NC + j + 1) * D + d] = pre * Wl[j] + kw[o];
      pre += buf[j * D + d];
    }
  }
}

// ---------------------------------------------------------------------------
// Kernel C (UNCHANGED from the verified baseline): scores+softmax.
// grid (16, BH): 8-row i-tile per block. Stages only the skp rows
// j <= i_max = T0+7 (XOR-swizzled) + the 8-row sq tile.
// Thread (jp, rep): cols {jp, jp+64}, rows {2rep, 2rep+1}. Col 128 never
// computed.
// ---------------------------------------------------------------------------
__global__ __launch_bounds__(256) void kC(const float* __restrict__ sq,
                                          const float* __restrict__ skp,
                                          float* __restrict__ out) {
  const int tile = blockIdx.x, b = blockIdx.y;
  const int tid = threadIdx.x;
  const int jp = tid & 63, rep = tid >> 6;
  const int T0 = tile * 8;
  const int rows = T0 + 8;   // skp rows needed: 0..T0+7

  __shared__ float skpS[NB * D];   // 32 KB max (only `rows` rows staged)
  __shared__ float sqs[8 * D];     // 2 KB

  {
    const float4* g4 = (const float4*)(skp + (size_t)b * NC * D);
    for (int u = tid; u < rows * 16; u += 256) {
      const int row = u >> 4, f = u & 15;
      ((float4*)skpS)[row * 16 + ((f + row) & 15)] = g4[u];
    }
    if (tid < 128)
      ((float4*)sqs)[tid] = ((const float4*)(sq + ((size_t)b * NB + T0) * D))[tid];
  }
  __syncthreads();

  float acc0[2] = {0, 0}, acc1[2] = {0, 0};
  const float4* sk4 = (const float4*)skpS;
  const float4* sq4 = (const float4*)sqs;
#pragma unroll
  for (int d4 = 0; d4 < 16; ++d4) {
    const int slot = (d4 + jp) & 15;           // same slot for jp and jp+64
    const float4 k0 = sk4[jp * 16 + slot];
    const float4 k1 = sk4[(jp + 64) * 16 + slot];
#pragma unroll
    for (int ii = 0; ii < 2; ++ii) {
      const float4 s = sq4[(rep * 2 + ii) * 16 + d4];
      acc0[ii] += s.x * k0.x + s.y * k0.y + s.z * k0.z + s.w * k0.w;
      acc1[ii] += s.x * k1.x + s.y * k1.y + s.z * k1.z + s.w * k1.w;
    }
  }

#pragma unroll
  for (int ii = 0; ii < 2; ++ii) {
    const int i = T0 + rep * 2 + ii;
    const int j0 = jp, j1 = jp + 64;
    const float v0 = acc0[ii] * 0.125f, v1 = acc1[ii] * 0.125f;
    const bool val0 = (j0 <= i), val1 = (j1 <= i);
    float m = fmaxf(val0 ? v0 : -3.402823466e38f, val1 ? v1 : -3.402823466e38f);
#pragma unroll
    for (int s = 1; s < 64; s <<= 1) m = fmaxf(m, __shfl_xor(m, s, 64));
    const float e0 = val0 ? __expf(v0 - m) : 0.0f;
    const float e1 = val1 ? __expf(v1 - m) : 0.0f;
    float ss = e0 + e1;
#pragma unroll
    for (int s = 1; s < 64; s <<= 1) ss += __shfl_xor(ss, s, 64);
    const float rden = 1.0f / ss;
    float* orow = out + ((size_t)b * NB + i) * NC;
    orow[j0] = (j0 < i) ? e0 * rden : 0.0f;
    orow[j1] = (j1 < i) ? e1 * rden : 0.0f;
    if (jp == 0) orow[128] = 0.0f;
  }
}

// ---------------------------------------------------------------------------
extern "C" void kernel_launch(void* const* d_in, const int* in_sizes, int n_in,
                              void* d_out, int out_size, void* d_ws, size_t ws_size,
                              hipStream_t stream) {
  const float* q = (const float*)d_in[0];
  const float* k = (const float*)d_in[1];
  float* out = (float*)d_out;

  float* ws     = (float*)d_ws;
  float* qsum   = ws;                            // BH*NB*D
  float* ksum   = qsum   + (size_t)BH * NB * D;
  float* kw     = ksum   + (size_t)BH * NB * D;
  float* qfirst = kw     + (size_t)BH * NB * D;
  float* sq     = qfirst + (size_t)BH * NB * D;
  float* skp    = sq     + (size_t)BH * NB * D;  // BH*NC*D
  float* W      = skp    + (size_t)BH * NC * D;  // NB

  kA<<<dim3(NB, BH), 256, 0, stream>>>(q, k, qsum, ksum, kw, qfirst, W);
  kB<<<dim3(2, BH), 512, 0, stream>>>(qsum, ksum, kw, qfirst, W, sq, skp);
  kC<<<dim3(16, BH), 256, 0, stream>>>(sq, skp, out);
}